// Round 11
// baseline (406.439 us; speedup 1.0000x reference)
//
#include <hip/hip_runtime.h>

typedef __attribute__((ext_vector_type(8))) short short8;
typedef __attribute__((ext_vector_type(4))) float floatx4;

#define CSC 0.1803368801f   // 0.125 * log2(e): folded score scale + exp2 base change

__device__ __forceinline__ unsigned short f2b(float f){
  unsigned int u = __builtin_bit_cast(unsigned int, f);
  unsigned int r = (u + 0x7fffu + ((u >> 16) & 1u)) >> 16;
  return (unsigned short)r;
}
__device__ __forceinline__ float b2f(unsigned short h){
  unsigned int u = ((unsigned int)h) << 16;
  return __builtin_bit_cast(float, u);
}
__device__ __forceinline__ floatx4 mfma16(short8 a, short8 b, floatx4 c){
  return __builtin_amdgcn_mfma_f32_16x16x32_bf16(a, b, c, 0, 0, 0);
}
// async global->LDS, 16B per lane, dest = wave-uniform base + lane*16 (linear)
__device__ __forceinline__ void gload_lds16(const unsigned short* g, unsigned short* l){
  __builtin_amdgcn_global_load_lds(
      (const __attribute__((address_space(1))) unsigned int*)g,
      (__attribute__((address_space(3))) unsigned int*)l, 16, 0, 0);
}

// ---------------------------------------------------------------------------
// Kernel 1 (fused prep): patch/Er bf16 convert + time projections + weight
// transpose. (R6 config, verified.)
// ---------------------------------------------------------------------------
__global__ __launch_bounds__(256) void prep_kernel(
    const float* __restrict__ patches, const float* __restrict__ Er,
    const float* __restrict__ temb,
    const float* __restrict__ Wqt, const float* __restrict__ bqt,
    const float* __restrict__ Wkt, const float* __restrict__ bkt,
    const float* __restrict__ Wvt, const float* __restrict__ bvt,
    const float* __restrict__ Wqs, const float* __restrict__ Wks,
    const float* __restrict__ Wvs,
    unsigned short* __restrict__ Pb, unsigned short* __restrict__ Erb,
    float* __restrict__ Tmat, unsigned short* __restrict__ Wb){
  int blk = blockIdx.x, tid = threadIdx.x;
  if (blk < 3104){
    const float* src; unsigned short* dst; int idx;
    if (blk < 3072){ idx = blk*2048 + tid*8; src = patches; dst = Pb; }
    else           { idx = (blk-3072)*2048 + tid*8; src = Er; dst = Erb; }
    float4 f0 = *(const float4*)(src + idx);
    float4 f1 = *(const float4*)(src + idx + 4);
    uint4 pk;
    pk.x = (unsigned)f2b(f0.x) | ((unsigned)f2b(f0.y)<<16);
    pk.y = (unsigned)f2b(f0.z) | ((unsigned)f2b(f0.w)<<16);
    pk.z = (unsigned)f2b(f1.x) | ((unsigned)f2b(f1.y)<<16);
    pk.w = (unsigned)f2b(f1.z) | ((unsigned)f2b(f1.w)<<16);
    *(uint4*)(dst + idx) = pk;
  } else if (blk < 3248){
    // time-projection partial: idx -> (g, bb, kc); K-chunk = 64
    int idx = blk - 3104;
    int g = idx / 48, rem = idx % 48, bb = rem / 6, kc = rem % 6;
    const float* Wt = (g==0)? Wqt : (g==1)? Wkt : Wvt;
    const float* bt = (g==0)? bqt : (g==1)? bkt : bvt;
    __shared__ float emb[64];
    if (tid < 64) emb[tid] = temb[bb*384 + kc*64 + tid];
    __syncthreads();
    float a0 = 0.f, a1 = 0.f, a2 = 0.f;
    #pragma unroll 8
    for (int t=0;t<64;t++){
      float e = emb[t];
      const float* wr = Wt + (kc*64 + t)*768;
      a0 += e*wr[tid]; a1 += e*wr[tid+256]; a2 += e*wr[tid+512];
    }
    if (kc == 0){ a0 += bt[tid]; a1 += bt[tid+256]; a2 += bt[tid+512]; }
    float s = (g==0) ? CSC : 1.0f;
    float* dst = Tmat + g*6144 + bb*768;
    atomicAdd(&dst[tid],     a0*s);
    atomicAdd(&dst[tid+256], a1*s);
    atomicAdd(&dst[tid+512], a2*s);
  } else {
    // weight transpose: tb in [0,432): g, then 12x12 tile grid
    int tb = blk - 3248;
    int g = tb / 144, rem = tb % 144;
    int by = rem / 12, bx = rem % 12;
    __shared__ float tile[64][65];
    const float* W = (g==0) ? Wqs : (g==1) ? Wks : Wvs;
    int r0 = by*64, c0 = bx*64;
    int tx = tid & 63, ty = tid >> 6;
    #pragma unroll
    for (int i=0;i<16;i++){
      int r = i*4 + ty;
      tile[r][tx] = W[(r0+r)*768 + c0 + tx];
    }
    __syncthreads();
    unsigned short* dst = Wb + g*589824;
    #pragma unroll
    for (int i=0;i<16;i++){
      int rr = i*4 + ty;
      dst[(c0+rr)*768 + r0 + tx] = f2b(tile[tx][rr]);
    }
  }
}

// ---------------------------------------------------------------------------
// Kernel 2: fused QKV GEMM — R6 config (128M x 192N, 768 blocks = 1 round,
// 2-barrier m97 structure, XOR source/read swizzle). Verified.
// ---------------------------------------------------------------------------
__global__ __launch_bounds__(256, 3) void qkv_gemm(
    const unsigned short* __restrict__ Pb, const unsigned short* __restrict__ Wb,
    const float* __restrict__ bq, const float* __restrict__ bk,
    const float* __restrict__ bv, const float* __restrict__ Tmat,
    unsigned short* __restrict__ Qs, unsigned short* __restrict__ K,
    unsigned short* __restrict__ V){
  __shared__ unsigned short smem_q[26112];   // staging: A 0..8191, B 8192..20479; V-epi 192x136
  unsigned short* a_lds = smem_q;
  unsigned short* b_lds = smem_q + 8192;
  int g = blockIdx.z;
  int m0 = blockIdx.x*128, n0 = blockIdx.y*192;
  int tid = threadIdx.x, w = tid>>6, lane = tid&63, quad = lane>>4, l16 = lane&15;
  int wr = w>>1, wc = w&1;
  const unsigned short* Wg = Wb + g*589824;
  const float* bias = (g==0)? bq : (g==1)? bk : bv;
  floatx4 acc[4][6];
  #pragma unroll
  for (int i=0;i<4;i++)
    #pragma unroll
    for (int j=0;j<6;j++) acc[i][j] = (floatx4){0.f,0.f,0.f,0.f};

  int rsub = lane>>3;
  int csw  = (((lane&7) ^ rsub) << 3);     // swizzled source col (shorts)
  int sw   = l16 & 7;                      // read-side XOR key (row&7)

  for (int kt=0; kt<12; kt++){
    int k0 = kt*64;
    __syncthreads();
    #pragma unroll
    for (int j=0;j<4;j++){
      int chunk = w*4 + j;
      int r = chunk*8 + rsub;
      gload_lds16(&Pb[(m0+r)*768 + k0 + csw], &a_lds[chunk*512]);
    }
    #pragma unroll
    for (int j=0;j<6;j++){
      int chunk = w*6 + j;
      int r = chunk*8 + rsub;
      gload_lds16(&Wg[(n0+r)*768 + k0 + csw], &b_lds[chunk*512]);
    }
    __syncthreads();   // vmcnt(0) drain (m97 structure)
    #pragma unroll
    for (int ks=0; ks<2; ks++){
      short8 af[4], bf[6];
      int cc = ((ks*4 + quad) ^ sw) << 3;  // swizzled read col (shorts)
      #pragma unroll
      for (int mb=0;mb<4;mb++)
        af[mb] = *(const short8*)&a_lds[(wr*64+mb*16+l16)*64 + cc];
      #pragma unroll
      for (int nb=0;nb<6;nb++)
        bf[nb] = *(const short8*)&b_lds[(wc*96+nb*16+l16)*64 + cc];
      #pragma unroll
      for (int mb=0;mb<4;mb++)
        #pragma unroll
        for (int nb=0;nb<6;nb++)
          acc[mb][nb] = mfma16(af[mb], bf[nb], acc[mb][nb]);
    }
  }
  if (g < 2){
    #pragma unroll
    for (int mb=0;mb<4;mb++)
    #pragma unroll
    for (int nb=0;nb<6;nb++)
    #pragma unroll
    for (int reg=0;reg<4;reg++){
      int m = m0 + wr*64 + mb*16 + quad*4 + reg;
      int n = n0 + wc*96 + nb*16 + l16;
      int bb = m >> 10, s = m & 1023, h = n >> 6, hd = n & 63;
      float v = acc[mb][nb][reg] + bias[n];
      int base = (bb*12 + h) << 16;
      if (g == 0){
        Qs[base + (s<<6) + hd] = f2b(v * CSC);
      } else {
        float tadd = Tmat[6144 + bb*768 + n];
        K[base + (s<<6) + hd] = f2b(v + tadd);
      }
    }
  } else {
    // V: write C-tile transposed into LDS (stride 136), then coalesced store
    __syncthreads();     // main-loop LDS reads complete
    int bb = m0 >> 10;
    #pragma unroll
    for (int mb=0;mb<4;mb++)
    #pragma unroll
    for (int nb=0;nb<6;nb++)
    #pragma unroll
    for (int reg=0;reg<4;reg++){
      int ml = wr*64 + mb*16 + quad*4 + reg;
      int nl = wc*96 + nb*16 + l16;
      int n = n0 + nl;
      float v = acc[mb][nb][reg] + bias[n] + Tmat[12288 + bb*768 + n];
      smem_q[nl*136 + ml] = f2b(v);
    }
    __syncthreads();
    int s0 = m0 & 1023;
    #pragma unroll
    for (int i=0;i<12;i++){
      int idx = i*256 + tid;
      int r = idx >> 4, c8 = (idx & 15) << 3;   // r: n_local (0..191), c8: m_local
      int n = n0 + r, h = n >> 6, hd = n & 63;
      int base = (bb*12 + h) << 16;
      *(uint4*)&V[base + (hd<<10) + s0 + c8] = *(const uint4*)&smem_q[r*136 + c8];
    }
  }
}

// ---------------------------------------------------------------------------
// Kernel 3: flash attention w/ skewed relative bias.
// R10->R11: KVBLK 64 -> 128. Stage 128 keys of K/V per iteration, then run
// the R1-frozen 64-key compute body TWICE (kk=0,1) against the two halves.
// Halves the barrier-drain count (32 -> 16 full vmcnt/lgkm drains, the
// all-waves-stalled mechanism behind MfmaUtil 10.4%). NO write/compute
// overlap (R4's failed dbuf) — the proven {sync,write,sync,compute}
// pattern is kept, only the tile grain changes. Band/softmax/PV body is
// character-identical with diag = k0 - q0 - sub*64, k0 = kt2*128 + kk*64.
// LDS 47104 B (K 128x72, V 64x136, pw 4x16x88) -> still 3 blocks/CU.
// Decision rule: attn >= 165us -> null -> revert to R10 config.
// ---------------------------------------------------------------------------
__global__ __launch_bounds__(256, 3) void attn_kernel(
    const unsigned short* __restrict__ Qsp, const unsigned short* __restrict__ Kp,
    const unsigned short* __restrict__ Vtp, const unsigned short* __restrict__ Erb,
    const float* __restrict__ Tq, float* __restrict__ out){
  __shared__ __align__(16) char smem[47104];
  unsigned short* k_lds  = (unsigned short*)smem;            // 128x72
  unsigned short* v_lds  = (unsigned short*)(smem + 18432);  // 64x136 (vT [hd][128key])
  unsigned short* pw_all = (unsigned short*)(smem + 35840);  // 4 x (16x88)

  int tid = threadIdx.x, w = tid>>6, lane = tid&63, quad = lane>>4, l16 = lane&15;
  unsigned short* pw = pw_all + w*1408;    // this wave's 16x88 region
  // XCD-aware decode: wg%8 selects XCD; keep one batch per XCD
  int wg = blockIdx.x;
  int b = wg & 7, slot = wg >> 3;
  int h = slot >> 3, q0 = (slot & 7) << 7;
  int hb = (b*12 + h) << 16;
  const unsigned short* Qsh = Qsp + hb;
  const unsigned short* Kh  = Kp  + hb;
  const unsigned short* Vh  = Vtp + hb;
  const float* tqv = Tq + b*768 + h*64;    // pre-scaled by CSC

  int frow = w*16 + l16;
  short8 qf[2][2], qlo[2][2], qhi[2][2];   // [sub][ks]
  #pragma unroll
  for (int sub=0; sub<2; sub++){
    int qrow = q0 + sub*64 + frow;
    int qrow1 = (qrow < 1023) ? qrow+1 : 1023;
    #pragma unroll
    for (int ks=0; ks<2; ks++){
      int c = ks*32 + quad*8;
      qlo[sub][ks] = *(const short8*)&Qsh[(qrow <<6) + c];
      qhi[sub][ks] = *(const short8*)&Qsh[(qrow1<<6) + c];
      float4 t0 = *(const float4*)&tqv[c];
      float4 t1 = *(const float4*)&tqv[c+4];
      short8 qq;
      qq[0]=(short)f2b(b2f((unsigned short)qlo[sub][ks][0])+t0.x);
      qq[1]=(short)f2b(b2f((unsigned short)qlo[sub][ks][1])+t0.y);
      qq[2]=(short)f2b(b2f((unsigned short)qlo[sub][ks][2])+t0.z);
      qq[3]=(short)f2b(b2f((unsigned short)qlo[sub][ks][3])+t0.w);
      qq[4]=(short)f2b(b2f((unsigned short)qlo[sub][ks][4])+t1.x);
      qq[5]=(short)f2b(b2f((unsigned short)qlo[sub][ks][5])+t1.y);
      qq[6]=(short)f2b(b2f((unsigned short)qlo[sub][ks][6])+t1.z);
      qq[7]=(short)f2b(b2f((unsigned short)qlo[sub][ks][7])+t1.w);
      qf[sub][ks] = qq;
    }
  }

  float lpart[2][4] = {{0.f,0.f,0.f,0.f},{0.f,0.f,0.f,0.f}};
  floatx4 o_acc[2][4];
  #pragma unroll
  for (int sub=0;sub<2;sub++)
    #pragma unroll
    for (int ob=0;ob<4;ob++) o_acc[sub][ob] = (floatx4){0.f,0.f,0.f,0.f};

  int ql = quad*4;           // + reg = within-wave q row
  int ub_lo = 3 - w;         // wave-w band blocks [3-w, 7-w]

  // K/V staging: 128-key tiles. Thread covers K rows sr,sr+32,sr+64,sr+96
  // (col chunk scc) and V rows sr,sr+32 at key cols scc and scc+64.
  int sr = tid>>3, scc = (tid&7)<<3;
  uint4 kr[4], vr[4];
  #pragma unroll
  for (int j=0;j<4;j++)
    kr[j] = *(const uint4*)&Kh[((j*32+sr)<<6) + scc];
  vr[0] = *(const uint4*)&Vh[(sr<<10) + scc];
  vr[1] = *(const uint4*)&Vh[((sr+32)<<10) + scc];
  vr[2] = *(const uint4*)&Vh[(sr<<10) + 64 + scc];
  vr[3] = *(const uint4*)&Vh[((sr+32)<<10) + 64 + scc];

  for (int kt2=0; kt2<8; kt2++){
    int k0b = kt2*128;
    __syncthreads();                       // all waves done reading k/v
    #pragma unroll
    for (int j=0;j<4;j++)
      *(uint4*)&k_lds[(j*32+sr)*72 + scc] = kr[j];
    *(uint4*)&v_lds[sr*136 + scc]           = vr[0];
    *(uint4*)&v_lds[(sr+32)*136 + scc]      = vr[1];
    *(uint4*)&v_lds[sr*136 + 64 + scc]      = vr[2];
    *(uint4*)&v_lds[(sr+32)*136 + 64 + scc] = vr[3];
    __syncthreads();
    // prefetch next 128-key tile (clamped re-load on last iter)
    int k0n = (kt2 < 7) ? k0b + 128 : k0b;
    #pragma unroll
    for (int j=0;j<4;j++)
      kr[j] = *(const uint4*)&Kh[((k0n + j*32 + sr)<<6) + scc];
    vr[0] = *(const uint4*)&Vh[(sr<<10) + k0n + scc];
    vr[1] = *(const uint4*)&Vh[((sr+32)<<10) + k0n + scc];
    vr[2] = *(const uint4*)&Vh[(sr<<10) + k0n + 64 + scc];
    vr[3] = *(const uint4*)&Vh[((sr+32)<<10) + k0n + 64 + scc];

    #pragma unroll
    for (int kk=0; kk<2; kk++){
      int k0 = k0b + kk*64;
      const unsigned short* kb = k_lds + (kk*64)*72;   // this half's K rows
      const unsigned short* vb = v_lds + kk*64;        // this half's V cols

      // ---- QK^T for both sub-tiles, sharing kf fragment reads ----
      floatx4 sc[2][4];
      __builtin_amdgcn_s_setprio(1);
      #pragma unroll
      for (int nb=0;nb<4;nb++){
        sc[0][nb] = (floatx4){0.f,0.f,0.f,0.f};
        sc[1][nb] = (floatx4){0.f,0.f,0.f,0.f};
        #pragma unroll
        for (int ks=0;ks<2;ks++){
          short8 kf = *(const short8*)&kb[(nb*16+l16)*72 + ks*32 + quad*8];
          sc[0][nb] = mfma16(qf[0][ks], kf, sc[0][nb]);
          sc[1][nb] = mfma16(qf[1][ks], kf, sc[1][nb]);
        }
      }
      __builtin_amdgcn_s_setprio(0);

      #pragma unroll
      for (int sub=0; sub<2; sub++){
        int diag = k0 - q0 - sub*64;
        bool needL = (diag <= 0), needU = (diag >= 0);
        bool needSel = (diag == 0) || (diag == 64);
        for (int pass=0; pass<2; pass++){
          if ((pass==0 && !needL) || (pass==1 && !needU)) continue;
          int tbase = (pass==0) ? (960 + diag) : (diag - 65);
          const short8* af = (pass==0) ? qlo[sub] : qhi[sub];
          // band GEMM: 5 ub blocks per wave, Er B-frags direct from global
          #pragma unroll
          for (int lb=0; lb<5; lb++){
            int ub = ub_lo + lb;
            int t = tbase + ub*16 + l16;
            t = (t < 0) ? 0 : (t > 1023 ? 1023 : t);
            floatx4 pa = (floatx4){0.f,0.f,0.f,0.f};
            #pragma unroll
            for (int ks=0;ks<2;ks++){
              short8 ef = *(const short8*)&Erb[(t<<6) + ks*32 + quad*8];
              pa = mfma16(af[ks], ef, pa);
            }
            #pragma unroll
            for (int reg=0;reg<4;reg++)
              pw[(ql + reg)*88 + lb*16 + l16] = f2b(pa[reg]);
          }
          // gather-add (wave-private; in-wave DS ordering)
          #pragma unroll
          for (int nb=0;nb<4;nb++)
          #pragma unroll
          for (int reg=0;reg<4;reg++){
            int qlr = ql + reg;
            int ki = nb*16 + l16;
            float bv = b2f(pw[qlr*88 + 15 + ki - qlr]);
            if (needSel){
              int kq = diag + ki - (w*16 + qlr);
              bool sel = (pass==0) ? (kq <= 0) : (kq >= 2);
              bv = sel ? bv : 0.f;
            }
            sc[sub][nb][reg] += bv;
          }
        }
        // ---- fixed-base softmax: p = 2^sc (scale folded into Q/Qs) ----
        #pragma unroll
        for (int nb=0;nb<4;nb++)
        #pragma unroll
        for (int reg=0;reg<4;reg++){
          float p = __builtin_amdgcn_exp2f(sc[sub][nb][reg]);
          lpart[sub][reg] += p;
          pw[(ql + reg)*88 + nb*16 + l16] = f2b(p);
        }
        short8 pf[2];
        #pragma unroll
        for (int ks=0;ks<2;ks++)
          pf[ks] = *(const short8*)&pw[l16*88 + ks*32 + quad*8];
        __builtin_amdgcn_s_setprio(1);
        #pragma unroll
        for (int ob=0;ob<4;ob++){
          #pragma unroll
          for (int ks=0;ks<2;ks++){
            short8 vf = *(const short8*)&vb[(ob*16+l16)*136 + ks*32 + quad*8];
            o_acc[sub][ob] = mfma16(pf[ks], vf, o_acc[sub][ob]);
          }
        }
        __builtin_amdgcn_s_setprio(0);
      }
    }
  }
  // final row-sum reduce (deferred; no per-tile rescale happened)
  #pragma unroll
  for (int sub=0;sub<2;sub++){
    float rl[4];
    #pragma unroll
    for (int reg=0;reg<4;reg++){
      float l = lpart[sub][reg];
      #pragma unroll
      for (int off=1; off<16; off<<=1) l += __shfl_xor(l, off);
      rl[reg] = __builtin_amdgcn_rcpf(l);
    }
    #pragma unroll
    for (int ob=0;ob<4;ob++)
    #pragma unroll
    for (int reg=0;reg<4;reg++){
      int s = q0 + sub*64 + w*16 + quad*4 + reg;
      out[((b<<10) + s)*768 + (h<<6) + ob*16 + l16] = o_acc[sub][ob][reg] * rl[reg];
    }
  }
}

// ---------------------------------------------------------------------------
extern "C" void kernel_launch(void* const* d_in, const int* in_sizes, int n_in,
                              void* d_out, int out_size, void* d_ws, size_t ws_size,
                              hipStream_t stream) {
  const float* patches  = (const float*)d_in[0];
  const float* time_emb = (const float*)d_in[1];
  const float* Wqs = (const float*)d_in[2];  const float* bqs = (const float*)d_in[3];
  const float* Wks = (const float*)d_in[4];  const float* bks = (const float*)d_in[5];
  const float* Wvs = (const float*)d_in[6];  const float* bvs = (const float*)d_in[7];
  const float* Wqt = (const float*)d_in[8];  const float* bqt = (const float*)d_in[9];
  const float* Wkt = (const float*)d_in[10]; const float* bkt = (const float*)d_in[11];
  const float* Wvt = (const float*)d_in[12]; const float* bvt = (const float*)d_in[13];
  const float* Er  = (const float*)d_in[14];

  unsigned short* Qsp  = (unsigned short*)d_ws;     // 6291456 (bf16, pre-scaled)
  unsigned short* Kp   = Qsp + 6291456;
  unsigned short* Vp   = Kp  + 6291456;             // transposed per head [hd][s]
  unsigned short* Wbp  = Vp  + 6291456;             // 3*589824, [g][n][k]
  unsigned short* Erbp = Wbp + 1769472;             // 65536
  unsigned short* Pbp  = Erbp + 65536;              // 6291456 (patches bf16)
  float*          Tmat = (float*)(Pbp + 6291456);   // 3*8*768 fp32 (g0 * CSC)

  float* out = (float*)d_out;

  hipMemsetAsync(Tmat, 0, 3*8*768*sizeof(float), stream);    // atomic partials
  hipLaunchKernelGGL(prep_kernel, dim3(3680), dim3(256), 0, stream,
                     patches, Er, time_emb, Wqt, bqt, Wkt, bkt, Wvt, bvt,
                     Wqs, Wks, Wvs, Pbp, Erbp, Tmat, Wbp);
  hipLaunchKernelGGL(qkv_gemm, dim3(64,4,3), dim3(256), 0, stream,
                     Pbp, Wbp, bqs, bks, bvs, Tmat, Qsp, Kp, Vp);
  hipLaunchKernelGGL(attn_kernel, dim3(768), dim3(256), 0, stream,
                     Qsp, Kp, Vp, Erbp, Tmat, out);
}

// Round 12
// 306.996 us; speedup vs baseline: 1.3239x; 1.3239x over previous
//
#include <hip/hip_runtime.h>

typedef __attribute__((ext_vector_type(8))) short short8;
typedef __attribute__((ext_vector_type(4))) float floatx4;

#define CSC 0.1803368801f   // 0.125 * log2(e): folded score scale + exp2 base change

__device__ __forceinline__ unsigned short f2b(float f){
  unsigned int u = __builtin_bit_cast(unsigned int, f);
  unsigned int r = (u + 0x7fffu + ((u >> 16) & 1u)) >> 16;
  return (unsigned short)r;
}
__device__ __forceinline__ float b2f(unsigned short h){
  unsigned int u = ((unsigned int)h) << 16;
  return __builtin_bit_cast(float, u);
}
__device__ __forceinline__ floatx4 mfma16(short8 a, short8 b, floatx4 c){
  return __builtin_amdgcn_mfma_f32_16x16x32_bf16(a, b, c, 0, 0, 0);
}
// async global->LDS, 16B per lane, dest = wave-uniform base + lane*16 (linear)
__device__ __forceinline__ void gload_lds16(const unsigned short* g, unsigned short* l){
  __builtin_amdgcn_global_load_lds(
      (const __attribute__((address_space(1))) unsigned int*)g,
      (__attribute__((address_space(3))) unsigned int*)l, 16, 0, 0);
}

// ---------------------------------------------------------------------------
// Kernel 1 (fused prep): patch/Er bf16 convert + time projections + weight
// transpose. (R6 config, verified.)
// ---------------------------------------------------------------------------
__global__ __launch_bounds__(256) void prep_kernel(
    const float* __restrict__ patches, const float* __restrict__ Er,
    const float* __restrict__ temb,
    const float* __restrict__ Wqt, const float* __restrict__ bqt,
    const float* __restrict__ Wkt, const float* __restrict__ bkt,
    const float* __restrict__ Wvt, const float* __restrict__ bvt,
    const float* __restrict__ Wqs, const float* __restrict__ Wks,
    const float* __restrict__ Wvs,
    unsigned short* __restrict__ Pb, unsigned short* __restrict__ Erb,
    float* __restrict__ Tmat, unsigned short* __restrict__ Wb){
  int blk = blockIdx.x, tid = threadIdx.x;
  if (blk < 3104){
    const float* src; unsigned short* dst; int idx;
    if (blk < 3072){ idx = blk*2048 + tid*8; src = patches; dst = Pb; }
    else           { idx = (blk-3072)*2048 + tid*8; src = Er; dst = Erb; }
    float4 f0 = *(const float4*)(src + idx);
    float4 f1 = *(const float4*)(src + idx + 4);
    uint4 pk;
    pk.x = (unsigned)f2b(f0.x) | ((unsigned)f2b(f0.y)<<16);
    pk.y = (unsigned)f2b(f0.z) | ((unsigned)f2b(f0.w)<<16);
    pk.z = (unsigned)f2b(f1.x) | ((unsigned)f2b(f1.y)<<16);
    pk.w = (unsigned)f2b(f1.z) | ((unsigned)f2b(f1.w)<<16);
    *(uint4*)(dst + idx) = pk;
  } else if (blk < 3248){
    // time-projection partial: idx -> (g, bb, kc); K-chunk = 64
    int idx = blk - 3104;
    int g = idx / 48, rem = idx % 48, bb = rem / 6, kc = rem % 6;
    const float* Wt = (g==0)? Wqt : (g==1)? Wkt : Wvt;
    const float* bt = (g==0)? bqt : (g==1)? bkt : bvt;
    __shared__ float emb[64];
    if (tid < 64) emb[tid] = temb[bb*384 + kc*64 + tid];
    __syncthreads();
    float a0 = 0.f, a1 = 0.f, a2 = 0.f;
    #pragma unroll 8
    for (int t=0;t<64;t++){
      float e = emb[t];
      const float* wr = Wt + (kc*64 + t)*768;
      a0 += e*wr[tid]; a1 += e*wr[tid+256]; a2 += e*wr[tid+512];
    }
    if (kc == 0){ a0 += bt[tid]; a1 += bt[tid+256]; a2 += bt[tid+512]; }
    float s = (g==0) ? CSC : 1.0f;
    float* dst = Tmat + g*6144 + bb*768;
    atomicAdd(&dst[tid],     a0*s);
    atomicAdd(&dst[tid+256], a1*s);
    atomicAdd(&dst[tid+512], a2*s);
  } else {
    // weight transpose: tb in [0,432): g, then 12x12 tile grid
    int tb = blk - 3248;
    int g = tb / 144, rem = tb % 144;
    int by = rem / 12, bx = rem % 12;
    __shared__ float tile[64][65];
    const float* W = (g==0) ? Wqs : (g==1) ? Wks : Wvs;
    int r0 = by*64, c0 = bx*64;
    int tx = tid & 63, ty = tid >> 6;
    #pragma unroll
    for (int i=0;i<16;i++){
      int r = i*4 + ty;
      tile[r][tx] = W[(r0+r)*768 + c0 + tx];
    }
    __syncthreads();
    unsigned short* dst = Wb + g*589824;
    #pragma unroll
    for (int i=0;i<16;i++){
      int rr = i*4 + ty;
      dst[(c0+rr)*768 + r0 + tx] = f2b(tile[tx][rr]);
    }
  }
}

// ---------------------------------------------------------------------------
// Kernel 2: fused QKV GEMM — R6 config (128M x 192N, 768 blocks = 1 round,
// 2-barrier m97 structure, XOR source/read swizzle). Verified.
// ---------------------------------------------------------------------------
__global__ __launch_bounds__(256, 3) void qkv_gemm(
    const unsigned short* __restrict__ Pb, const unsigned short* __restrict__ Wb,
    const float* __restrict__ bq, const float* __restrict__ bk,
    const float* __restrict__ bv, const float* __restrict__ Tmat,
    unsigned short* __restrict__ Qs, unsigned short* __restrict__ K,
    unsigned short* __restrict__ V){
  __shared__ unsigned short smem_q[26112];   // staging: A 0..8191, B 8192..20479; V-epi 192x136
  unsigned short* a_lds = smem_q;
  unsigned short* b_lds = smem_q + 8192;
  int g = blockIdx.z;
  int m0 = blockIdx.x*128, n0 = blockIdx.y*192;
  int tid = threadIdx.x, w = tid>>6, lane = tid&63, quad = lane>>4, l16 = lane&15;
  int wr = w>>1, wc = w&1;
  const unsigned short* Wg = Wb + g*589824;
  const float* bias = (g==0)? bq : (g==1)? bk : bv;
  floatx4 acc[4][6];
  #pragma unroll
  for (int i=0;i<4;i++)
    #pragma unroll
    for (int j=0;j<6;j++) acc[i][j] = (floatx4){0.f,0.f,0.f,0.f};

  int rsub = lane>>3;
  int csw  = (((lane&7) ^ rsub) << 3);     // swizzled source col (shorts)
  int sw   = l16 & 7;                      // read-side XOR key (row&7)

  for (int kt=0; kt<12; kt++){
    int k0 = kt*64;
    __syncthreads();
    #pragma unroll
    for (int j=0;j<4;j++){
      int chunk = w*4 + j;
      int r = chunk*8 + rsub;
      gload_lds16(&Pb[(m0+r)*768 + k0 + csw], &a_lds[chunk*512]);
    }
    #pragma unroll
    for (int j=0;j<6;j++){
      int chunk = w*6 + j;
      int r = chunk*8 + rsub;
      gload_lds16(&Wg[(n0+r)*768 + k0 + csw], &b_lds[chunk*512]);
    }
    __syncthreads();   // vmcnt(0) drain (m97 structure)
    #pragma unroll
    for (int ks=0; ks<2; ks++){
      short8 af[4], bf[6];
      int cc = ((ks*4 + quad) ^ sw) << 3;  // swizzled read col (shorts)
      #pragma unroll
      for (int mb=0;mb<4;mb++)
        af[mb] = *(const short8*)&a_lds[(wr*64+mb*16+l16)*64 + cc];
      #pragma unroll
      for (int nb=0;nb<6;nb++)
        bf[nb] = *(const short8*)&b_lds[(wc*96+nb*16+l16)*64 + cc];
      #pragma unroll
      for (int mb=0;mb<4;mb++)
        #pragma unroll
        for (int nb=0;nb<6;nb++)
          acc[mb][nb] = mfma16(af[mb], bf[nb], acc[mb][nb]);
    }
  }
  if (g < 2){
    #pragma unroll
    for (int mb=0;mb<4;mb++)
    #pragma unroll
    for (int nb=0;nb<6;nb++)
    #pragma unroll
    for (int reg=0;reg<4;reg++){
      int m = m0 + wr*64 + mb*16 + quad*4 + reg;
      int n = n0 + wc*96 + nb*16 + l16;
      int bb = m >> 10, s = m & 1023, h = n >> 6, hd = n & 63;
      float v = acc[mb][nb][reg] + bias[n];
      int base = (bb*12 + h) << 16;
      if (g == 0){
        Qs[base + (s<<6) + hd] = f2b(v * CSC);
      } else {
        float tadd = Tmat[6144 + bb*768 + n];
        K[base + (s<<6) + hd] = f2b(v + tadd);
      }
    }
  } else {
    // V: write C-tile transposed into LDS (stride 136), then coalesced store
    __syncthreads();     // main-loop LDS reads complete
    int bb = m0 >> 10;
    #pragma unroll
    for (int mb=0;mb<4;mb++)
    #pragma unroll
    for (int nb=0;nb<6;nb++)
    #pragma unroll
    for (int reg=0;reg<4;reg++){
      int ml = wr*64 + mb*16 + quad*4 + reg;
      int nl = wc*96 + nb*16 + l16;
      int n = n0 + nl;
      float v = acc[mb][nb][reg] + bias[n] + Tmat[12288 + bb*768 + n];
      smem_q[nl*136 + ml] = f2b(v);
    }
    __syncthreads();
    int s0 = m0 & 1023;
    #pragma unroll
    for (int i=0;i<12;i++){
      int idx = i*256 + tid;
      int r = idx >> 4, c8 = (idx & 15) << 3;   // r: n_local (0..191), c8: m_local
      int n = n0 + r, h = n >> 6, hd = n & 63;
      int base = (bb*12 + h) << 16;
      *(uint4*)&V[base + (hd<<10) + s0 + c8] = *(const uint4*)&smem_q[r*136 + c8];
    }
  }
}

// ---------------------------------------------------------------------------
// Kernel 3: flash attention w/ skewed relative bias — R1-exact config
// (harness-verified 160.4-168.7 µs across R1/R5/R6/R7/R10). q128, 4 waves,
// single K/V buffer, 2 barriers/tile, register prefetch, XCD 1D decode,
// setprio. FROZEN — the R1 body sits exactly at the register budget:
// R2 q64-split (-60%, dispatch rounds), R4 dbuf (-14%), R8 atomic K-split
// (-107%, WRITE storm), R11 KVBLK-128 (-60%, scratch spill: +32 VGPR of
// prefetch state at VGPR=84 cap -> 340MB spill WRITE). Any added live
// state spills; any grid growth adds dispatch rounds.
// ---------------------------------------------------------------------------
__global__ __launch_bounds__(256, 3) void attn_kernel(
    const unsigned short* __restrict__ Qsp, const unsigned short* __restrict__ Kp,
    const unsigned short* __restrict__ Vtp, const unsigned short* __restrict__ Erb,
    const float* __restrict__ Tq, float* __restrict__ out){
  __shared__ __align__(16) char smem[29696];
  unsigned short* k_lds  = (unsigned short*)smem;            // 64x72
  unsigned short* v_lds  = (unsigned short*)(smem + 9216);   // 64x72 (vT [hd][key])
  unsigned short* pw_all = (unsigned short*)(smem + 18432);  // 4 x (16x88)

  int tid = threadIdx.x, w = tid>>6, lane = tid&63, quad = lane>>4, l16 = lane&15;
  unsigned short* pw = pw_all + w*1408;    // this wave's 16x88 region
  // XCD-aware decode: wg%8 selects XCD; keep one batch per XCD
  int wg = blockIdx.x;
  int b = wg & 7, slot = wg >> 3;
  int h = slot >> 3, q0 = (slot & 7) << 7;
  int hb = (b*12 + h) << 16;
  const unsigned short* Qsh = Qsp + hb;
  const unsigned short* Kh  = Kp  + hb;
  const unsigned short* Vh  = Vtp + hb;
  const float* tqv = Tq + b*768 + h*64;    // pre-scaled by CSC

  int frow = w*16 + l16;
  short8 qf[2][2], qlo[2][2], qhi[2][2];   // [sub][ks]
  #pragma unroll
  for (int sub=0; sub<2; sub++){
    int qrow = q0 + sub*64 + frow;
    int qrow1 = (qrow < 1023) ? qrow+1 : 1023;
    #pragma unroll
    for (int ks=0; ks<2; ks++){
      int c = ks*32 + quad*8;
      qlo[sub][ks] = *(const short8*)&Qsh[(qrow <<6) + c];
      qhi[sub][ks] = *(const short8*)&Qsh[(qrow1<<6) + c];
      float4 t0 = *(const float4*)&tqv[c];
      float4 t1 = *(const float4*)&tqv[c+4];
      short8 qq;
      qq[0]=(short)f2b(b2f((unsigned short)qlo[sub][ks][0])+t0.x);
      qq[1]=(short)f2b(b2f((unsigned short)qlo[sub][ks][1])+t0.y);
      qq[2]=(short)f2b(b2f((unsigned short)qlo[sub][ks][2])+t0.z);
      qq[3]=(short)f2b(b2f((unsigned short)qlo[sub][ks][3])+t0.w);
      qq[4]=(short)f2b(b2f((unsigned short)qlo[sub][ks][4])+t1.x);
      qq[5]=(short)f2b(b2f((unsigned short)qlo[sub][ks][5])+t1.y);
      qq[6]=(short)f2b(b2f((unsigned short)qlo[sub][ks][6])+t1.z);
      qq[7]=(short)f2b(b2f((unsigned short)qlo[sub][ks][7])+t1.w);
      qf[sub][ks] = qq;
    }
  }

  float lpart[2][4] = {{0.f,0.f,0.f,0.f},{0.f,0.f,0.f,0.f}};
  floatx4 o_acc[2][4];
  #pragma unroll
  for (int sub=0;sub<2;sub++)
    #pragma unroll
    for (int ob=0;ob<4;ob++) o_acc[sub][ob] = (floatx4){0.f,0.f,0.f,0.f};

  int ql = quad*4;           // + reg = within-wave q row
  int ub_lo = 3 - w;         // wave-w band blocks [3-w, 7-w]

  // K/V staging addressing: thread covers rows sr, sr+32 (col chunk scc)
  int sr = tid>>3, scc = (tid&7)<<3;
  uint4 kr0, kr1, vr0, vr1;
  kr0 = *(const uint4*)&Kh[(sr<<6) + scc];
  kr1 = *(const uint4*)&Kh[((sr+32)<<6) + scc];
  vr0 = *(const uint4*)&Vh[(sr<<10) + scc];
  vr1 = *(const uint4*)&Vh[((sr+32)<<10) + scc];

  for (int kt=0; kt<16; kt++){
    int k0 = kt*64;
    __syncthreads();                       // all waves done reading k/v
    *(uint4*)&k_lds[sr*72 + scc]      = kr0;
    *(uint4*)&k_lds[(sr+32)*72 + scc] = kr1;
    *(uint4*)&v_lds[sr*72 + scc]      = vr0;
    *(uint4*)&v_lds[(sr+32)*72 + scc] = vr1;
    __syncthreads();
    // prefetch next k-tile (clamped re-load of tile 15 on last iter)
    int k0n = (kt < 15) ? k0 + 64 : k0;
    kr0 = *(const uint4*)&Kh[((k0n+sr)<<6) + scc];
    kr1 = *(const uint4*)&Kh[((k0n+sr+32)<<6) + scc];
    vr0 = *(const uint4*)&Vh[(sr<<10) + k0n + scc];
    vr1 = *(const uint4*)&Vh[((sr+32)<<10) + k0n + scc];

    // ---- QK^T for both sub-tiles, sharing kf fragment reads ----
    floatx4 sc[2][4];
    __builtin_amdgcn_s_setprio(1);
    #pragma unroll
    for (int nb=0;nb<4;nb++){
      sc[0][nb] = (floatx4){0.f,0.f,0.f,0.f};
      sc[1][nb] = (floatx4){0.f,0.f,0.f,0.f};
      #pragma unroll
      for (int ks=0;ks<2;ks++){
        short8 kf = *(const short8*)&k_lds[(nb*16+l16)*72 + ks*32 + quad*8];
        sc[0][nb] = mfma16(qf[0][ks], kf, sc[0][nb]);
        sc[1][nb] = mfma16(qf[1][ks], kf, sc[1][nb]);
      }
    }
    __builtin_amdgcn_s_setprio(0);

    #pragma unroll
    for (int sub=0; sub<2; sub++){
      int diag = k0 - q0 - sub*64;
      bool needL = (diag <= 0), needU = (diag >= 0);
      bool needSel = (diag == 0) || (diag == 64);
      for (int pass=0; pass<2; pass++){
        if ((pass==0 && !needL) || (pass==1 && !needU)) continue;
        int tbase = (pass==0) ? (960 + diag) : (diag - 65);
        const short8* af = (pass==0) ? qlo[sub] : qhi[sub];
        // band GEMM: 5 ub blocks per wave, Er B-frags direct from global
        #pragma unroll
        for (int lb=0; lb<5; lb++){
          int ub = ub_lo + lb;
          int t = tbase + ub*16 + l16;
          t = (t < 0) ? 0 : (t > 1023 ? 1023 : t);
          floatx4 pa = (floatx4){0.f,0.f,0.f,0.f};
          #pragma unroll
          for (int ks=0;ks<2;ks++){
            short8 ef = *(const short8*)&Erb[(t<<6) + ks*32 + quad*8];
            pa = mfma16(af[ks], ef, pa);
          }
          #pragma unroll
          for (int reg=0;reg<4;reg++)
            pw[(ql + reg)*88 + lb*16 + l16] = f2b(pa[reg]);
        }
        // gather-add (wave-private; in-wave DS ordering)
        #pragma unroll
        for (int nb=0;nb<4;nb++)
        #pragma unroll
        for (int reg=0;reg<4;reg++){
          int qlr = ql + reg;
          int ki = nb*16 + l16;
          float bv = b2f(pw[qlr*88 + 15 + ki - qlr]);
          if (needSel){
            int kq = diag + ki - (w*16 + qlr);
            bool sel = (pass==0) ? (kq <= 0) : (kq >= 2);
            bv = sel ? bv : 0.f;
          }
          sc[sub][nb][reg] += bv;
        }
      }
      // ---- fixed-base softmax: p = 2^sc (scale folded into Q/Qs) ----
      #pragma unroll
      for (int nb=0;nb<4;nb++)
      #pragma unroll
      for (int reg=0;reg<4;reg++){
        float p = __builtin_amdgcn_exp2f(sc[sub][nb][reg]);
        lpart[sub][reg] += p;
        pw[(ql + reg)*88 + nb*16 + l16] = f2b(p);
      }
      short8 pf[2];
      #pragma unroll
      for (int ks=0;ks<2;ks++)
        pf[ks] = *(const short8*)&pw[l16*88 + ks*32 + quad*8];
      __builtin_amdgcn_s_setprio(1);
      #pragma unroll
      for (int ob=0;ob<4;ob++){
        #pragma unroll
        for (int ks=0;ks<2;ks++){
          short8 vf = *(const short8*)&v_lds[(ob*16+l16)*72 + ks*32 + quad*8];
          o_acc[sub][ob] = mfma16(pf[ks], vf, o_acc[sub][ob]);
        }
      }
      __builtin_amdgcn_s_setprio(0);
    }
  }
  // final row-sum reduce (deferred; no per-tile rescale happened)
  #pragma unroll
  for (int sub=0;sub<2;sub++){
    float rl[4];
    #pragma unroll
    for (int reg=0;reg<4;reg++){
      float l = lpart[sub][reg];
      #pragma unroll
      for (int off=1; off<16; off<<=1) l += __shfl_xor(l, off);
      rl[reg] = __builtin_amdgcn_rcpf(l);
    }
    #pragma unroll
    for (int ob=0;ob<4;ob++)
    #pragma unroll
    for (int reg=0;reg<4;reg++){
      int s = q0 + sub*64 + w*16 + quad*4 + reg;
      out[((b<<10) + s)*768 + (h<<6) + ob*16 + l16] = o_acc[sub][ob][reg] * rl[reg];
    }
  }
}

// ---------------------------------------------------------------------------
extern "C" void kernel_launch(void* const* d_in, const int* in_sizes, int n_in,
                              void* d_out, int out_size, void* d_ws, size_t ws_size,
                              hipStream_t stream) {
  const float* patches  = (const float*)d_in[0];
  const float* time_emb = (const float*)d_in[1];
  const float* Wqs = (const float*)d_in[2];  const float* bqs = (const float*)d_in[3];
  const float* Wks = (const float*)d_in[4];  const float* bks = (const float*)d_in[5];
  const float* Wvs = (const float*)d_in[6];  const float* bvs = (const float*)d_in[7];
  const float* Wqt = (const float*)d_in[8];  const float* bqt = (const float*)d_in[9];
  const float* Wkt = (const float*)d_in[10]; const float* bkt = (const float*)d_in[11];
  const float* Wvt = (const float*)d_in[12]; const float* bvt = (const float*)d_in[13];
  const float* Er  = (const float*)d_in[14];

  unsigned short* Qsp  = (unsigned short*)d_ws;     // 6291456 (bf16, pre-scaled)
  unsigned short* Kp   = Qsp + 6291456;
  unsigned short* Vp   = Kp  + 6291456;             // transposed per head [hd][s]
  unsigned short* Wbp  = Vp  + 6291456;             // 3*589824, [g][n][k]
  unsigned short* Erbp = Wbp + 1769472;             // 65536
  unsigned short* Pbp  = Erbp + 65536;              // 6291456 (patches bf16)
  float*          Tmat = (float*)(Pbp + 6291456);   // 3*8*768 fp32 (g0 * CSC)

  float* out = (float*)d_out;

  hipMemsetAsync(Tmat, 0, 3*8*768*sizeof(float), stream);    // atomic partials
  hipLaunchKernelGGL(prep_kernel, dim3(3680), dim3(256), 0, stream,
                     patches, Er, time_emb, Wqt, bqt, Wkt, bkt, Wvt, bvt,
                     Wqs, Wks, Wvs, Pbp, Erbp, Tmat, Wbp);
  hipLaunchKernelGGL(qkv_gemm, dim3(64,4,3), dim3(256), 0, stream,
                     Pbp, Wbp, bqs, bks, bvs, Tmat, Qsp, Kp, Vp);
  hipLaunchKernelGGL(attn_kernel, dim3(768), dim3(256), 0, stream,
                     Qsp, Kp, Vp, Erbp, Tmat, out);
}

// Round 13
// 302.718 us; speedup vs baseline: 1.3426x; 1.0141x over previous
//
#include <hip/hip_runtime.h>

typedef __attribute__((ext_vector_type(8))) short short8;
typedef __attribute__((ext_vector_type(4))) float floatx4;

#define CSC 0.1803368801f   // 0.125 * log2(e): folded score scale + exp2 base change

__device__ __forceinline__ unsigned short f2b(float f){
  unsigned int u = __builtin_bit_cast(unsigned int, f);
  unsigned int r = (u + 0x7fffu + ((u >> 16) & 1u)) >> 16;
  return (unsigned short)r;
}
__device__ __forceinline__ float b2f(unsigned short h){
  unsigned int u = ((unsigned int)h) << 16;
  return __builtin_bit_cast(float, u);
}
__device__ __forceinline__ floatx4 mfma16(short8 a, short8 b, floatx4 c){
  return __builtin_amdgcn_mfma_f32_16x16x32_bf16(a, b, c, 0, 0, 0);
}
// async global->LDS, 16B per lane, dest = wave-uniform base + lane*16 (linear)
__device__ __forceinline__ void gload_lds16(const unsigned short* g, unsigned short* l){
  __builtin_amdgcn_global_load_lds(
      (const __attribute__((address_space(1))) unsigned int*)g,
      (__attribute__((address_space(3))) unsigned int*)l, 16, 0, 0);
}

// ---------------------------------------------------------------------------
// Kernel 1 (fused prep): patch/Er bf16 convert + time projections + weight
// transpose. (R6 config, verified.)
// ---------------------------------------------------------------------------
__global__ __launch_bounds__(256) void prep_kernel(
    const float* __restrict__ patches, const float* __restrict__ Er,
    const float* __restrict__ temb,
    const float* __restrict__ Wqt, const float* __restrict__ bqt,
    const float* __restrict__ Wkt, const float* __restrict__ bkt,
    const float* __restrict__ Wvt, const float* __restrict__ bvt,
    const float* __restrict__ Wqs, const float* __restrict__ Wks,
    const float* __restrict__ Wvs,
    unsigned short* __restrict__ Pb, unsigned short* __restrict__ Erb,
    float* __restrict__ Tmat, unsigned short* __restrict__ Wb){
  int blk = blockIdx.x, tid = threadIdx.x;
  if (blk < 3104){
    const float* src; unsigned short* dst; int idx;
    if (blk < 3072){ idx = blk*2048 + tid*8; src = patches; dst = Pb; }
    else           { idx = (blk-3072)*2048 + tid*8; src = Er; dst = Erb; }
    float4 f0 = *(const float4*)(src + idx);
    float4 f1 = *(const float4*)(src + idx + 4);
    uint4 pk;
    pk.x = (unsigned)f2b(f0.x) | ((unsigned)f2b(f0.y)<<16);
    pk.y = (unsigned)f2b(f0.z) | ((unsigned)f2b(f0.w)<<16);
    pk.z = (unsigned)f2b(f1.x) | ((unsigned)f2b(f1.y)<<16);
    pk.w = (unsigned)f2b(f1.z) | ((unsigned)f2b(f1.w)<<16);
    *(uint4*)(dst + idx) = pk;
  } else if (blk < 3248){
    // time-projection partial: idx -> (g, bb, kc); K-chunk = 64
    int idx = blk - 3104;
    int g = idx / 48, rem = idx % 48, bb = rem / 6, kc = rem % 6;
    const float* Wt = (g==0)? Wqt : (g==1)? Wkt : Wvt;
    const float* bt = (g==0)? bqt : (g==1)? bkt : bvt;
    __shared__ float emb[64];
    if (tid < 64) emb[tid] = temb[bb*384 + kc*64 + tid];
    __syncthreads();
    float a0 = 0.f, a1 = 0.f, a2 = 0.f;
    #pragma unroll 8
    for (int t=0;t<64;t++){
      float e = emb[t];
      const float* wr = Wt + (kc*64 + t)*768;
      a0 += e*wr[tid]; a1 += e*wr[tid+256]; a2 += e*wr[tid+512];
    }
    if (kc == 0){ a0 += bt[tid]; a1 += bt[tid+256]; a2 += bt[tid+512]; }
    float s = (g==0) ? CSC : 1.0f;
    float* dst = Tmat + g*6144 + bb*768;
    atomicAdd(&dst[tid],     a0*s);
    atomicAdd(&dst[tid+256], a1*s);
    atomicAdd(&dst[tid+512], a2*s);
  } else {
    // weight transpose: tb in [0,432): g, then 12x12 tile grid
    int tb = blk - 3248;
    int g = tb / 144, rem = tb % 144;
    int by = rem / 12, bx = rem % 12;
    __shared__ float tile[64][65];
    const float* W = (g==0) ? Wqs : (g==1) ? Wks : Wvs;
    int r0 = by*64, c0 = bx*64;
    int tx = tid & 63, ty = tid >> 6;
    #pragma unroll
    for (int i=0;i<16;i++){
      int r = i*4 + ty;
      tile[r][tx] = W[(r0+r)*768 + c0 + tx];
    }
    __syncthreads();
    unsigned short* dst = Wb + g*589824;
    #pragma unroll
    for (int i=0;i<16;i++){
      int rr = i*4 + ty;
      dst[(c0+rr)*768 + r0 + tx] = f2b(tile[tx][rr]);
    }
  }
}

// ---------------------------------------------------------------------------
// Kernel 2: fused QKV GEMM — R6 config (128M x 192N, 768 blocks = 1 round,
// 2-barrier m97 structure, XOR source/read swizzle). Verified.
// ---------------------------------------------------------------------------
__global__ __launch_bounds__(256, 3) void qkv_gemm(
    const unsigned short* __restrict__ Pb, const unsigned short* __restrict__ Wb,
    const float* __restrict__ bq, const float* __restrict__ bk,
    const float* __restrict__ bv, const float* __restrict__ Tmat,
    unsigned short* __restrict__ Qs, unsigned short* __restrict__ K,
    unsigned short* __restrict__ V){
  __shared__ unsigned short smem_q[26112];   // staging: A 0..8191, B 8192..20479; V-epi 192x136
  unsigned short* a_lds = smem_q;
  unsigned short* b_lds = smem_q + 8192;
  int g = blockIdx.z;
  int m0 = blockIdx.x*128, n0 = blockIdx.y*192;
  int tid = threadIdx.x, w = tid>>6, lane = tid&63, quad = lane>>4, l16 = lane&15;
  int wr = w>>1, wc = w&1;
  const unsigned short* Wg = Wb + g*589824;
  const float* bias = (g==0)? bq : (g==1)? bk : bv;
  floatx4 acc[4][6];
  #pragma unroll
  for (int i=0;i<4;i++)
    #pragma unroll
    for (int j=0;j<6;j++) acc[i][j] = (floatx4){0.f,0.f,0.f,0.f};

  int rsub = lane>>3;
  int csw  = (((lane&7) ^ rsub) << 3);     // swizzled source col (shorts)
  int sw   = l16 & 7;                      // read-side XOR key (row&7)

  for (int kt=0; kt<12; kt++){
    int k0 = kt*64;
    __syncthreads();
    #pragma unroll
    for (int j=0;j<4;j++){
      int chunk = w*4 + j;
      int r = chunk*8 + rsub;
      gload_lds16(&Pb[(m0+r)*768 + k0 + csw], &a_lds[chunk*512]);
    }
    #pragma unroll
    for (int j=0;j<6;j++){
      int chunk = w*6 + j;
      int r = chunk*8 + rsub;
      gload_lds16(&Wg[(n0+r)*768 + k0 + csw], &b_lds[chunk*512]);
    }
    __syncthreads();   // vmcnt(0) drain (m97 structure)
    #pragma unroll
    for (int ks=0; ks<2; ks++){
      short8 af[4], bf[6];
      int cc = ((ks*4 + quad) ^ sw) << 3;  // swizzled read col (shorts)
      #pragma unroll
      for (int mb=0;mb<4;mb++)
        af[mb] = *(const short8*)&a_lds[(wr*64+mb*16+l16)*64 + cc];
      #pragma unroll
      for (int nb=0;nb<6;nb++)
        bf[nb] = *(const short8*)&b_lds[(wc*96+nb*16+l16)*64 + cc];
      #pragma unroll
      for (int mb=0;mb<4;mb++)
        #pragma unroll
        for (int nb=0;nb<6;nb++)
          acc[mb][nb] = mfma16(af[mb], bf[nb], acc[mb][nb]);
    }
  }
  if (g < 2){
    #pragma unroll
    for (int mb=0;mb<4;mb++)
    #pragma unroll
    for (int nb=0;nb<6;nb++)
    #pragma unroll
    for (int reg=0;reg<4;reg++){
      int m = m0 + wr*64 + mb*16 + quad*4 + reg;
      int n = n0 + wc*96 + nb*16 + l16;
      int bb = m >> 10, s = m & 1023, h = n >> 6, hd = n & 63;
      float v = acc[mb][nb][reg] + bias[n];
      int base = (bb*12 + h) << 16;
      if (g == 0){
        Qs[base + (s<<6) + hd] = f2b(v * CSC);
      } else {
        float tadd = Tmat[6144 + bb*768 + n];
        K[base + (s<<6) + hd] = f2b(v + tadd);
      }
    }
  } else {
    // V: write C-tile transposed into LDS (stride 136), then coalesced store
    __syncthreads();     // main-loop LDS reads complete
    int bb = m0 >> 10;
    #pragma unroll
    for (int mb=0;mb<4;mb++)
    #pragma unroll
    for (int nb=0;nb<6;nb++)
    #pragma unroll
    for (int reg=0;reg<4;reg++){
      int ml = wr*64 + mb*16 + quad*4 + reg;
      int nl = wc*96 + nb*16 + l16;
      int n = n0 + nl;
      float v = acc[mb][nb][reg] + bias[n] + Tmat[12288 + bb*768 + n];
      smem_q[nl*136 + ml] = f2b(v);
    }
    __syncthreads();
    int s0 = m0 & 1023;
    #pragma unroll
    for (int i=0;i<12;i++){
      int idx = i*256 + tid;
      int r = idx >> 4, c8 = (idx & 15) << 3;   // r: n_local (0..191), c8: m_local
      int n = n0 + r, h = n >> 6, hd = n & 63;
      int base = (bb*12 + h) << 16;
      *(uint4*)&V[base + (hd<<10) + s0 + c8] = *(const uint4*)&smem_q[r*136 + c8];
    }
  }
}

// ---------------------------------------------------------------------------
// Kernel 3: flash attention w/ skewed relative bias — R1-exact structure
// (harness-verified 160.4-168.7 µs across R1/R5/R6/R7/R10/R12). q128, 4
// waves, single K/V buffer, 2 barriers/tile, register prefetch, XCD 1D
// decode. FROZEN body — every structural edit regressed (R2 q64 -60%,
// R4 dbuf -14%, R8 atomic K-split -107%, R11 KVBLK-128 spill -60%).
// R12->R13 sole delta: s_setprio(1) around the band-GEMM MFMA cluster
// (the only unwrapped MFMA cluster; zero register/LDS/layout change —
// same T5 class as R1's QK^T/PV wrap). Revert rule: attn > 165us.
// ---------------------------------------------------------------------------
__global__ __launch_bounds__(256, 3) void attn_kernel(
    const unsigned short* __restrict__ Qsp, const unsigned short* __restrict__ Kp,
    const unsigned short* __restrict__ Vtp, const unsigned short* __restrict__ Erb,
    const float* __restrict__ Tq, float* __restrict__ out){
  __shared__ __align__(16) char smem[29696];
  unsigned short* k_lds  = (unsigned short*)smem;            // 64x72
  unsigned short* v_lds  = (unsigned short*)(smem + 9216);   // 64x72 (vT [hd][key])
  unsigned short* pw_all = (unsigned short*)(smem + 18432);  // 4 x (16x88)

  int tid = threadIdx.x, w = tid>>6, lane = tid&63, quad = lane>>4, l16 = lane&15;
  unsigned short* pw = pw_all + w*1408;    // this wave's 16x88 region
  // XCD-aware decode: wg%8 selects XCD; keep one batch per XCD
  int wg = blockIdx.x;
  int b = wg & 7, slot = wg >> 3;
  int h = slot >> 3, q0 = (slot & 7) << 7;
  int hb = (b*12 + h) << 16;
  const unsigned short* Qsh = Qsp + hb;
  const unsigned short* Kh  = Kp  + hb;
  const unsigned short* Vh  = Vtp + hb;
  const float* tqv = Tq + b*768 + h*64;    // pre-scaled by CSC

  int frow = w*16 + l16;
  short8 qf[2][2], qlo[2][2], qhi[2][2];   // [sub][ks]
  #pragma unroll
  for (int sub=0; sub<2; sub++){
    int qrow = q0 + sub*64 + frow;
    int qrow1 = (qrow < 1023) ? qrow+1 : 1023;
    #pragma unroll
    for (int ks=0; ks<2; ks++){
      int c = ks*32 + quad*8;
      qlo[sub][ks] = *(const short8*)&Qsh[(qrow <<6) + c];
      qhi[sub][ks] = *(const short8*)&Qsh[(qrow1<<6) + c];
      float4 t0 = *(const float4*)&tqv[c];
      float4 t1 = *(const float4*)&tqv[c+4];
      short8 qq;
      qq[0]=(short)f2b(b2f((unsigned short)qlo[sub][ks][0])+t0.x);
      qq[1]=(short)f2b(b2f((unsigned short)qlo[sub][ks][1])+t0.y);
      qq[2]=(short)f2b(b2f((unsigned short)qlo[sub][ks][2])+t0.z);
      qq[3]=(short)f2b(b2f((unsigned short)qlo[sub][ks][3])+t0.w);
      qq[4]=(short)f2b(b2f((unsigned short)qlo[sub][ks][4])+t1.x);
      qq[5]=(short)f2b(b2f((unsigned short)qlo[sub][ks][5])+t1.y);
      qq[6]=(short)f2b(b2f((unsigned short)qlo[sub][ks][6])+t1.z);
      qq[7]=(short)f2b(b2f((unsigned short)qlo[sub][ks][7])+t1.w);
      qf[sub][ks] = qq;
    }
  }

  float lpart[2][4] = {{0.f,0.f,0.f,0.f},{0.f,0.f,0.f,0.f}};
  floatx4 o_acc[2][4];
  #pragma unroll
  for (int sub=0;sub<2;sub++)
    #pragma unroll
    for (int ob=0;ob<4;ob++) o_acc[sub][ob] = (floatx4){0.f,0.f,0.f,0.f};

  int ql = quad*4;           // + reg = within-wave q row
  int ub_lo = 3 - w;         // wave-w band blocks [3-w, 7-w]

  // K/V staging addressing: thread covers rows sr, sr+32 (col chunk scc)
  int sr = tid>>3, scc = (tid&7)<<3;
  uint4 kr0, kr1, vr0, vr1;
  kr0 = *(const uint4*)&Kh[(sr<<6) + scc];
  kr1 = *(const uint4*)&Kh[((sr+32)<<6) + scc];
  vr0 = *(const uint4*)&Vh[(sr<<10) + scc];
  vr1 = *(const uint4*)&Vh[((sr+32)<<10) + scc];

  for (int kt=0; kt<16; kt++){
    int k0 = kt*64;
    __syncthreads();                       // all waves done reading k/v
    *(uint4*)&k_lds[sr*72 + scc]      = kr0;
    *(uint4*)&k_lds[(sr+32)*72 + scc] = kr1;
    *(uint4*)&v_lds[sr*72 + scc]      = vr0;
    *(uint4*)&v_lds[(sr+32)*72 + scc] = vr1;
    __syncthreads();
    // prefetch next k-tile (clamped re-load of tile 15 on last iter)
    int k0n = (kt < 15) ? k0 + 64 : k0;
    kr0 = *(const uint4*)&Kh[((k0n+sr)<<6) + scc];
    kr1 = *(const uint4*)&Kh[((k0n+sr+32)<<6) + scc];
    vr0 = *(const uint4*)&Vh[(sr<<10) + k0n + scc];
    vr1 = *(const uint4*)&Vh[((sr+32)<<10) + k0n + scc];

    // ---- QK^T for both sub-tiles, sharing kf fragment reads ----
    floatx4 sc[2][4];
    __builtin_amdgcn_s_setprio(1);
    #pragma unroll
    for (int nb=0;nb<4;nb++){
      sc[0][nb] = (floatx4){0.f,0.f,0.f,0.f};
      sc[1][nb] = (floatx4){0.f,0.f,0.f,0.f};
      #pragma unroll
      for (int ks=0;ks<2;ks++){
        short8 kf = *(const short8*)&k_lds[(nb*16+l16)*72 + ks*32 + quad*8];
        sc[0][nb] = mfma16(qf[0][ks], kf, sc[0][nb]);
        sc[1][nb] = mfma16(qf[1][ks], kf, sc[1][nb]);
      }
    }
    __builtin_amdgcn_s_setprio(0);

    #pragma unroll
    for (int sub=0; sub<2; sub++){
      int diag = k0 - q0 - sub*64;
      bool needL = (diag <= 0), needU = (diag >= 0);
      bool needSel = (diag == 0) || (diag == 64);
      for (int pass=0; pass<2; pass++){
        if ((pass==0 && !needL) || (pass==1 && !needU)) continue;
        int tbase = (pass==0) ? (960 + diag) : (diag - 65);
        const short8* af = (pass==0) ? qlo[sub] : qhi[sub];
        // band GEMM: 5 ub blocks per wave, Er B-frags direct from global
        __builtin_amdgcn_s_setprio(1);     // R13: T5 wrap on band cluster
        #pragma unroll
        for (int lb=0; lb<5; lb++){
          int ub = ub_lo + lb;
          int t = tbase + ub*16 + l16;
          t = (t < 0) ? 0 : (t > 1023 ? 1023 : t);
          floatx4 pa = (floatx4){0.f,0.f,0.f,0.f};
          #pragma unroll
          for (int ks=0;ks<2;ks++){
            short8 ef = *(const short8*)&Erb[(t<<6) + ks*32 + quad*8];
            pa = mfma16(af[ks], ef, pa);
          }
          #pragma unroll
          for (int reg=0;reg<4;reg++)
            pw[(ql + reg)*88 + lb*16 + l16] = f2b(pa[reg]);
        }
        __builtin_amdgcn_s_setprio(0);
        // gather-add (wave-private; in-wave DS ordering)
        #pragma unroll
        for (int nb=0;nb<4;nb++)
        #pragma unroll
        for (int reg=0;reg<4;reg++){
          int qlr = ql + reg;
          int ki = nb*16 + l16;
          float bv = b2f(pw[qlr*88 + 15 + ki - qlr]);
          if (needSel){
            int kq = diag + ki - (w*16 + qlr);
            bool sel = (pass==0) ? (kq <= 0) : (kq >= 2);
            bv = sel ? bv : 0.f;
          }
          sc[sub][nb][reg] += bv;
        }
      }
      // ---- fixed-base softmax: p = 2^sc (scale folded into Q/Qs) ----
      #pragma unroll
      for (int nb=0;nb<4;nb++)
      #pragma unroll
      for (int reg=0;reg<4;reg++){
        float p = __builtin_amdgcn_exp2f(sc[sub][nb][reg]);
        lpart[sub][reg] += p;
        pw[(ql + reg)*88 + nb*16 + l16] = f2b(p);
      }
      short8 pf[2];
      #pragma unroll
      for (int ks=0;ks<2;ks++)
        pf[ks] = *(const short8*)&pw[l16*88 + ks*32 + quad*8];
      __builtin_amdgcn_s_setprio(1);
      #pragma unroll
      for (int ob=0;ob<4;ob++){
        #pragma unroll
        for (int ks=0;ks<2;ks++){
          short8 vf = *(const short8*)&v_lds[(ob*16+l16)*72 + ks*32 + quad*8];
          o_acc[sub][ob] = mfma16(pf[ks], vf, o_acc[sub][ob]);
        }
      }
      __builtin_amdgcn_s_setprio(0);
    }
  }
  // final row-sum reduce (deferred; no per-tile rescale happened)
  #pragma unroll
  for (int sub=0;sub<2;sub++){
    float rl[4];
    #pragma unroll
    for (int reg=0;reg<4;reg++){
      float l = lpart[sub][reg];
      #pragma unroll
      for (int off=1; off<16; off<<=1) l += __shfl_xor(l, off);
      rl[reg] = __builtin_amdgcn_rcpf(l);
    }
    #pragma unroll
    for (int ob=0;ob<4;ob++)
    #pragma unroll
    for (int reg=0;reg<4;reg++){
      int s = q0 + sub*64 + w*16 + quad*4 + reg;
      out[((b<<10) + s)*768 + (h<<6) + ob*16 + l16] = o_acc[sub][ob][reg] * rl[reg];
    }
  }
}

// ---------------------------------------------------------------------------
extern "C" void kernel_launch(void* const* d_in, const int* in_sizes, int n_in,
                              void* d_out, int out_size, void* d_ws, size_t ws_size,
                              hipStream_t stream) {
  const float* patches  = (const float*)d_in[0];
  const float* time_emb = (const float*)d_in[1];
  const float* Wqs = (const float*)d_in[2];  const float* bqs = (const float*)d_in[3];
  const float* Wks = (const float*)d_in[4];  const float* bks = (const float*)d_in[5];
  const float* Wvs = (const float*)d_in[6];  const float* bvs = (const float*)d_in[7];
  const float* Wqt = (const float*)d_in[8];  const float* bqt = (const float*)d_in[9];
  const float* Wkt = (const float*)d_in[10]; const float* bkt = (const float*)d_in[11];
  const float* Wvt = (const float*)d_in[12]; const float* bvt = (const float*)d_in[13];
  const float* Er  = (const float*)d_in[14];

  unsigned short* Qsp  = (unsigned short*)d_ws;     // 6291456 (bf16, pre-scaled)
  unsigned short* Kp   = Qsp + 6291456;
  unsigned short* Vp   = Kp  + 6291456;             // transposed per head [hd][s]
  unsigned short* Wbp  = Vp  + 6291456;             // 3*589824, [g][n][k]
  unsigned short* Erbp = Wbp + 1769472;             // 65536
  unsigned short* Pbp  = Erbp + 65536;              // 6291456 (patches bf16)
  float*          Tmat = (float*)(Pbp + 6291456);   // 3*8*768 fp32 (g0 * CSC)

  float* out = (float*)d_out;

  hipMemsetAsync(Tmat, 0, 3*8*768*sizeof(float), stream);    // atomic partials
  hipLaunchKernelGGL(prep_kernel, dim3(3680), dim3(256), 0, stream,
                     patches, Er, time_emb, Wqt, bqt, Wkt, bkt, Wvt, bvt,
                     Wqs, Wks, Wvs, Pbp, Erbp, Tmat, Wbp);
  hipLaunchKernelGGL(qkv_gemm, dim3(64,4,3), dim3(256), 0, stream,
                     Pbp, Wbp, bqs, bks, bvs, Tmat, Qsp, Kp, Vp);
  hipLaunchKernelGGL(attn_kernel, dim3(768), dim3(256), 0, stream,
                     Qsp, Kp, Vp, Erbp, Tmat, out);
}